// Round 8
// baseline (179.920 us; speedup 1.0000x reference)
//
#include <hip/hip_runtime.h>

// MLP3D fused, MI355X gfx950 — round 15: intra-block anti-phase via
// group-local spin barriers.
// Evidence recap: MFMA demand 19.8us/CU + VALU 18.5us/CU vs 48.6us wall ->
// the pipes are serialized by block-wide lockstep phases. r12/r13 failed on
// register entanglement (spills), r14's cross-block sleep missed the pairing.
// r15 removes both failure modes:
//   - grid = 256 blocks x 512 threads, LDS 135KB -> exactly 1 block/CU,
//     8 waves = 2/SIMD (same occupancy as r11). No co-residency guessing.
//   - 2 groups x 4 waves; SAME code path, group-indexed data (actX[g],
//     occ_s[g], barrier[g]) -> register profile identical to r11's proven
//     128 arch + 128 AGPR (nothing extra live across heavy phases).
//   - group-local sense-reversing barrier in LDS (ds_atomic cnt + gen spin)
//     replaces s_barrier -> groups run phase-independent.
//   - stagger: g1 waits until g0 signals after its first "h ready" (~3.5us)
//     -> g0's MFMA-heavy L1/L2 overlaps g1's VALU-heavy PE/L0; each SIMD
//     holds one wave of each group.
// Per-wave compute bodies are r11's verified code (48.9us, passing).

#define NPTS 131072
#define M_PB 128
#define AST 256
#define PPB 512   // points per block

typedef _Float16 half8   __attribute__((ext_vector_type(8)));
typedef _Float16 half4_t __attribute__((ext_vector_type(4)));
typedef __fp16   fp16x2  __attribute__((ext_vector_type(2)));
typedef float    float4_t __attribute__((ext_vector_type(4)));

// ---- prep: W (f32 [K][256]) -> f16 per-wave-contiguous fragment layout ----
__global__ void prep(const float* __restrict__ W0, const float* __restrict__ W1,
                     const float* __restrict__ W2, _Float16* __restrict__ ws) {
  int id = blockIdx.x * 256 + threadIdx.x;   // 147456 total
  _Float16 v;
  if (id < 16384) {            // W0sw: 4 slices x 2 kb x 4 tn x 512
    int e = id, j = e & 7, l = (e >> 3) & 63, tn = (e >> 9) & 3, kb = (e >> 11) & 1, s = e >> 12;
    int k = kb * 32 + (l >> 4) * 8 + j, n = s * 64 + tn * 16 + (l & 15);
    v = (k < 63) ? (_Float16)W0[k * 256 + n] : (_Float16)0.f;
  } else if (id < 81920) {     // W1sw: 4 x 8 x 4 x 512
    int e = id - 16384, j = e & 7, l = (e >> 3) & 63, tn = (e >> 9) & 3, kb = (e >> 11) & 7, s = e >> 14;
    int k = kb * 32 + (l >> 4) * 8 + j, n = s * 64 + tn * 16 + (l & 15);
    v = (_Float16)W1[k * 256 + n];
  } else {                     // W2sw
    int e = id - 81920, j = e & 7, l = (e >> 3) & 63, tn = (e >> 9) & 3, kb = (e >> 11) & 7, s = e >> 14;
    int k = kb * 32 + (l >> 4) * 8 + j, n = s * 64 + tn * 16 + (l & 15);
    v = (_Float16)W2[k * 256 + n];
  }
  ws[id] = v;
}

__device__ __forceinline__ half4_t pack4(float a, float b, float cc, float d) {
  fp16x2 p0 = __builtin_amdgcn_cvt_pkrtz(a, b);
  fp16x2 p1 = __builtin_amdgcn_cvt_pkrtz(cc, d);
  half4_t h;
  h[0] = (_Float16)p0[0]; h[1] = (_Float16)p0[1];
  h[2] = (_Float16)p1[0]; h[3] = (_Float16)p1[1];
  return h;
}

__global__ __launch_bounds__(512, 1) void mlp_main(
    const float* __restrict__ coords,
    const _Float16* __restrict__ W0sw,
    const _Float16* __restrict__ W1sw,
    const _Float16* __restrict__ W2sw,
    const float* __restrict__ b0, const float* __restrict__ b1,
    const float* __restrict__ b2,
    const float* __restrict__ Wocc, const float* __restrict__ bocc,
    const float* __restrict__ Wc, const float* __restrict__ bc,
    float* __restrict__ out) {
  __shared__ _Float16 actX[2][M_PB * AST];   // per-group activation buffer
  __shared__ float occ_s[2][4][M_PB];
  __shared__ int gcnt[2];
  __shared__ int ggen[2];
  __shared__ int sflag;

  const int t = threadIdx.x;
  const int g = t >> 8;          // wave-group (waves 0-3 / 4-7)
  const int tl = t & 255;        // thread id within group
  const int w = (t >> 6) & 3;    // wave-in-group = neuron slice = part id
  const int l = t & 63;
  const int c = l & 15;
  const int q = l >> 4;
  const int sx = c & 7;          // swizzle key for rows tm*16+c

  if (t == 0) { gcnt[0] = gcnt[1] = 0; ggen[0] = ggen[1] = 0; sflag = 0; }
  __syncthreads();               // the ONLY block-wide barrier

  // group-local sense-reversing barrier (4 waves)
  auto gbar = [&]() {
    __threadfence_block();                       // drain my LDS writes
    volatile int* vgen = (volatile int*)&ggen[g];
    int mygen = *vgen;                           // uniform across group
    if (l == 0) {
      if (atomicAdd(&gcnt[g], 1) == 3) {
        gcnt[g] = 0;
        __threadfence_block();
        atomicAdd(&ggen[g], 1);                  // release
      }
    }
    while (*vgen == mygen) __builtin_amdgcn_s_sleep(1);
    __threadfence_block();
  };

  _Float16* aX = actX[g];
  const _Float16* rp = aX + c * AST;   // row base for B-reads (row = tm*16+c)

  // stagger: group 1 holds until group 0 passes its first "h ready"
  if (g == 1) {
    volatile int* f = (volatile int*)&sflag;
    while (*f == 0) __builtin_amdgcn_s_sleep(4);
  }

  float4_t acc[4][8];

#pragma unroll 1
  for (int it = 0; it < 2; ++it) {
    const int m0 = blockIdx.x * PPB + g * 256 + it * 128;

    // ---- layer-0 weight fragments (live PE->L0 only) ----
    half8 a0[4], a1[4];
    {
      const _Float16* wb = W0sw + (size_t)w * 4096 + l * 8;
#pragma unroll
      for (int tn = 0; tn < 4; ++tn) {
        a0[tn] = *(const half8*)(wb + tn * 512);
        a1[tn] = *(const half8*)(wb + 2048 + tn * 512);
      }
    }

    // ---- positional encoding: 2 threads/point, 32 k-values each ----
    {
      int m = tl & 127, kh = (tl >> 7) * 32;
      const int cb = (tl >> 7) * 4;
      const int sm = m & 7;
      const float* cp = coords + (size_t)(m0 + m) * 3;
      float x0 = cp[0], x1 = cp[1], x2 = cp[2];
#pragma unroll
      for (int i = 0; i < 4; ++i) {
        float v[8];
#pragma unroll
        for (int u = 0; u < 8; ++u) {
          int k = kh + i * 8 + u;
          float r;
          if (k >= 63) r = 0.f;
          else if (k < 3) r = (k == 0) ? x0 : (k == 1 ? x1 : x2);
          else {
            int kk = k - 3;
            int f = kk / 6;
            int rem = kk - 6 * f;
            int s = (rem >= 3) ? 1 : 0;
            int i3 = rem - 3 * s;
            float xi = (i3 == 0) ? x0 : (i3 == 1 ? x1 : x2);
            float arg = xi * (float)(1 << f);
            float nn = rintf(arg * 0.15915494309189535f);
            float rr = fmaf(nn, -6.28318548202514648f, arg);
            rr = fmaf(nn, 1.7484555e-7f, rr);
            r = s ? __cosf(rr) : __sinf(rr);
          }
          v[u] = r;
        }
        half8 ev;
#pragma unroll
        for (int u = 0; u < 4; ++u) {
          fp16x2 p = __builtin_amdgcn_cvt_pkrtz(v[2 * u], v[2 * u + 1]);
          ev[2 * u] = (_Float16)p[0]; ev[2 * u + 1] = (_Float16)p[1];
        }
        *(half8*)&aX[m * AST + (((cb + i) ^ sm) << 3)] = ev;
      }
    }
    gbar();                                   // (1) E ready

    // ---- layer 0: h = E @ W0 + b0 (no relu) ----
    {
#pragma unroll
      for (int tn = 0; tn < 4; ++tn) {
        float4_t bz = *(const float4_t*)(b0 + 64 * w + tn * 16 + q * 4);
#pragma unroll
        for (int tm = 0; tm < 8; ++tm) acc[tn][tm] = bz;
      }
#pragma unroll
      for (int kb = 0; kb < 2; ++kb) {
        const int cx = ((kb * 4 + q) ^ sx) << 3;
        half8 b[8];
#pragma unroll
        for (int tm = 0; tm < 8; ++tm) b[tm] = *(const half8*)(rp + tm * 16 * AST + cx);
#pragma unroll
        for (int tn = 0; tn < 4; ++tn)
#pragma unroll
          for (int tm = 0; tm < 8; ++tm)
            acc[tn][tm] = __builtin_amdgcn_mfma_f32_16x16x32_f16(
                kb ? a1[tn] : a0[tn], b[tm], acc[tn][tm], 0, 0, 0);
      }
    }
    gbar();                                   // (2) all E reads done
#pragma unroll
    for (int tn = 0; tn < 4; ++tn) {
      const int sc = ((8 * w + 2 * tn + (q >> 1)) ^ sx) * 8 + (q & 1) * 4;
#pragma unroll
      for (int tm = 0; tm < 8; ++tm) {
        float4_t v = acc[tn][tm];
        *(half4_t*)&aX[(tm * 16 + c) * AST + sc] = pack4(v[0], v[1], v[2], v[3]);
      }
    }
    gbar();                                   // (3) h ready

    if (g == 0 && it == 0 && t == 0) {
      *(volatile int*)&sflag = 1;             // release group 1 (stagger)
    }

    // ---- layer 1 (+ part head): masked kb pair FIRST, snapshot after j==1 ----
    {
      const _Float16* wb = W1sw + (size_t)w * 16384 + l * 8;
      const int w2 = 2 * w;
      float bcw = bc[w];
#pragma unroll
      for (int tn = 0; tn < 4; ++tn) {
        float4_t bz = *(const float4_t*)(b1 + 64 * w + tn * 16 + q * 4);
#pragma unroll
        for (int tm = 0; tm < 8; ++tm) acc[tn][tm] = bz;
      }
      auto kbof = [&](int j) {
        return (j < 2) ? (w2 + j) : ((j - 2) + ((j - 2) >= w2 ? 2 : 0));
      };
      half8 A[3][4];
#pragma unroll
      for (int p = 0; p < 3; ++p) {
        const _Float16* pa = wb + kbof(p) * 2048;
#pragma unroll
        for (int tn = 0; tn < 4; ++tn) A[p][tn] = *(const half8*)(pa + tn * 512);
      }
#pragma unroll
      for (int j = 0; j < 8; ++j) {
        const int kb = kbof(j);
        const int cx = ((kb * 4 + q) ^ sx) << 3;
        half8 b[8];
#pragma unroll
        for (int tm = 0; tm < 8; ++tm) b[tm] = *(const half8*)(rp + tm * 16 * AST + cx);
        // consume A[j%3] BEFORE the lookahead-3 prefetch overwrites it
        __builtin_amdgcn_s_setprio(1);
#pragma unroll
        for (int tn = 0; tn < 4; ++tn)
#pragma unroll
          for (int tm = 0; tm < 8; ++tm)
            acc[tn][tm] = __builtin_amdgcn_mfma_f32_16x16x32_f16(
                A[j % 3][tn], b[tm], acc[tn][tm], 0, 0, 0);
        __builtin_amdgcn_s_setprio(0);
        if (j == 1) {
          float pcls[8] = {0.f, 0.f, 0.f, 0.f, 0.f, 0.f, 0.f, 0.f};
#pragma unroll
          for (int tn = 0; tn < 4; ++tn) {
            float4_t wcv = *(const float4_t*)(Wc + 256 * w + 64 * w + tn * 16 + q * 4);
#pragma unroll
            for (int tm = 0; tm < 8; ++tm) {
              float4_t v = acc[tn][tm];
#pragma unroll
              for (int r = 0; r < 4; ++r) pcls[tm] += fmaxf(v[r], 0.f) * wcv[r];
            }
          }
#pragma unroll
          for (int tm = 0; tm < 8; ++tm) {
            float s = pcls[tm];
            s += __shfl_xor(s, 16, 64);
            s += __shfl_xor(s, 32, 64);
            if (l < 16)
              out[(size_t)NPTS + (size_t)(m0 + tm * 16 + c) * 4 + w] = s + bcw;
          }
        }
        if (j + 3 < 8) {   // prefetch AFTER use
          const _Float16* pa = wb + kbof(j + 3) * 2048;
#pragma unroll
          for (int tn = 0; tn < 4; ++tn) A[j % 3][tn] = *(const half8*)(pa + tn * 512);
        }
      }
    }
    gbar();                                   // (4) all h reads done
#pragma unroll
    for (int tn = 0; tn < 4; ++tn) {
      const int sc = ((8 * w + 2 * tn + (q >> 1)) ^ sx) * 8 + (q & 1) * 4;
#pragma unroll
      for (int tm = 0; tm < 8; ++tm) {
        float4_t v = acc[tn][tm];
        *(half4_t*)&aX[(tm * 16 + c) * AST + sc] =
            pack4(fmaxf(v[0], 0.f), fmaxf(v[1], 0.f), fmaxf(v[2], 0.f), fmaxf(v[3], 0.f));
      }
    }
    gbar();                                   // (5) t1 ready

    // ---- layer 2 + occ head ----
    {
      const _Float16* wb = W2sw + (size_t)w * 16384 + l * 8;
#pragma unroll
      for (int tn = 0; tn < 4; ++tn) {
        float4_t bz = *(const float4_t*)(b2 + 64 * w + tn * 16 + q * 4);
#pragma unroll
        for (int tm = 0; tm < 8; ++tm) acc[tn][tm] = bz;
      }
      half8 A[3][4];
#pragma unroll
      for (int p = 0; p < 3; ++p)
#pragma unroll
        for (int tn = 0; tn < 4; ++tn)
          A[p][tn] = *(const half8*)(wb + p * 2048 + tn * 512);
#pragma unroll
      for (int kb = 0; kb < 8; ++kb) {
        const int cx = ((kb * 4 + q) ^ sx) << 3;
        half8 b[8];
#pragma unroll
        for (int tm = 0; tm < 8; ++tm) b[tm] = *(const half8*)(rp + tm * 16 * AST + cx);
        __builtin_amdgcn_s_setprio(1);
#pragma unroll
        for (int tn = 0; tn < 4; ++tn)
#pragma unroll
          for (int tm = 0; tm < 8; ++tm)
            acc[tn][tm] = __builtin_amdgcn_mfma_f32_16x16x32_f16(
                A[kb % 3][tn], b[tm], acc[tn][tm], 0, 0, 0);
        __builtin_amdgcn_s_setprio(0);
        if (kb + 3 < 8) {
#pragma unroll
          for (int tn = 0; tn < 4; ++tn)
            A[kb % 3][tn] = *(const half8*)(wb + (kb + 3) * 2048 + tn * 512);
        }
      }
      float pocc[8] = {0.f, 0.f, 0.f, 0.f, 0.f, 0.f, 0.f, 0.f};
#pragma unroll
      for (int tn = 0; tn < 4; ++tn) {
        float4_t wov = *(const float4_t*)(Wocc + 64 * w + tn * 16 + q * 4);
#pragma unroll
        for (int tm = 0; tm < 8; ++tm) {
          float4_t v = acc[tn][tm];
#pragma unroll
          for (int r = 0; r < 4; ++r) pocc[tm] += fmaxf(v[r], 0.f) * wov[r];
        }
      }
#pragma unroll
      for (int tm = 0; tm < 8; ++tm) {
        float s = pocc[tm];
        s += __shfl_xor(s, 16, 64);
        s += __shfl_xor(s, 32, 64);
        if (l < 16) occ_s[g][w][tm * 16 + c] = s;
      }
    }
    gbar();                                   // (6) occ partials ready
    if (tl < M_PB) {
      out[m0 + tl] = occ_s[g][0][tl] + occ_s[g][1][tl] +
                     occ_s[g][2][tl] + occ_s[g][3][tl] + bocc[0];
    }
  }
}

extern "C" void kernel_launch(void* const* d_in, const int* in_sizes, int n_in,
                              void* d_out, int out_size, void* d_ws, size_t ws_size,
                              hipStream_t stream) {
  const float* coords = (const float*)d_in[0];
  const float* W0   = (const float*)d_in[1];
  const float* b0   = (const float*)d_in[2];
  const float* W1   = (const float*)d_in[3];
  const float* b1   = (const float*)d_in[4];
  const float* W2   = (const float*)d_in[5];
  const float* b2   = (const float*)d_in[6];
  const float* Wocc = (const float*)d_in[7];
  const float* bocc = (const float*)d_in[8];
  const float* Wc   = (const float*)d_in[9];
  const float* bc   = (const float*)d_in[10];
  float* out = (float*)d_out;

  _Float16* ws = (_Float16*)d_ws;       // W0sw[16384] | W1sw[65536] | W2sw[65536]
  _Float16* W0sw = ws;
  _Float16* W1sw = ws + 16384;
  _Float16* W2sw = ws + 81920;

  prep<<<576, 256, 0, stream>>>(W0, W1, W2, ws);
  mlp_main<<<NPTS / PPB, 512, 0, stream>>>(coords, W0sw, W1sw, W2sw,
                                           b0, b1, b2, Wocc, bocc, Wc, bc, out);
}

// Round 9
// 125.222 us; speedup vs baseline: 1.4368x; 1.4368x over previous
//
#include <hip/hip_runtime.h>

// MLP3D fused, MI355X gfx950 — round 16: PE hoisted to its own kernel,
// E consumed register-direct from global; 4 barriers instead of 6.
// History: r12/r13/r15 (512-thread anti-phase variants) all spilled ~100MB
// scratch with identical per-wave code and identical 256-reg budget ->
// unexplained compiler behavior, structure abandoned after 3 strikes.
// r14 (cross-block sleep) refuted the dispatch-pairing guess. Base = r11.
// This round removes the only VALU phase that can leave the kernel:
//   pe<<<2048,256>>>: 4 thr/point, 16 k-values each, writes E[131072][64]
//     f16 to workspace (coalesced 32B/thread stores). ~3-5us at full chip.
//   mlp_main_g: E loaded global->register (16 x b128/wave, issued at entry,
//     L2/HBM latency hidden under W0-frag loads + acc init). No E in LDS ->
//     PE phase, E-store, and barriers (1)+(2) deleted. Flow:
//     [E+W0 loads] -> L0 -> store-h -> bar -> L1+cls -> bar -> store-t1
//     -> bar -> L2+occ -> bar -> reduce.
// Fallback: if ws_size can't hold E (16.8MB), launch mlp_main_l = r11
// verbatim (48.9us verified) so worst case equals current perf.

#define NPTS 131072
#define M_PB 128
#define AST 256

typedef _Float16 half8   __attribute__((ext_vector_type(8)));
typedef _Float16 half4_t __attribute__((ext_vector_type(4)));
typedef __fp16   fp16x2  __attribute__((ext_vector_type(2)));
typedef float    float4_t __attribute__((ext_vector_type(4)));

// ---- prep: W (f32 [K][256]) -> f16 per-wave-contiguous fragment layout ----
// dst[(((s*KB + kb)*4 + tn)*64 + l)*8 + j] = W[(kb*32 + (l>>4)*8 + j)*256 + s*64 + tn*16 + (l&15)]
__global__ void prep(const float* __restrict__ W0, const float* __restrict__ W1,
                     const float* __restrict__ W2, _Float16* __restrict__ ws) {
  int id = blockIdx.x * 256 + threadIdx.x;   // 147456 total
  _Float16 v;
  if (id < 16384) {            // W0sw: 4 slices x 2 kb x 4 tn x 512
    int e = id, j = e & 7, l = (e >> 3) & 63, tn = (e >> 9) & 3, kb = (e >> 11) & 1, s = e >> 12;
    int k = kb * 32 + (l >> 4) * 8 + j, n = s * 64 + tn * 16 + (l & 15);
    v = (k < 63) ? (_Float16)W0[k * 256 + n] : (_Float16)0.f;
  } else if (id < 81920) {     // W1sw: 4 x 8 x 4 x 512
    int e = id - 16384, j = e & 7, l = (e >> 3) & 63, tn = (e >> 9) & 3, kb = (e >> 11) & 7, s = e >> 14;
    int k = kb * 32 + (l >> 4) * 8 + j, n = s * 64 + tn * 16 + (l & 15);
    v = (_Float16)W1[k * 256 + n];
  } else {                     // W2sw
    int e = id - 81920, j = e & 7, l = (e >> 3) & 63, tn = (e >> 9) & 3, kb = (e >> 11) & 7, s = e >> 14;
    int k = kb * 32 + (l >> 4) * 8 + j, n = s * 64 + tn * 16 + (l & 15);
    v = (_Float16)W2[k * 256 + n];
  }
  ws[id] = v;
}

__device__ __forceinline__ half4_t pack4(float a, float b, float cc, float d) {
  union { half4_t h; fp16x2 p[2]; } u;
  u.p[0] = __builtin_amdgcn_cvt_pkrtz(a, b);
  u.p[1] = __builtin_amdgcn_cvt_pkrtz(cc, d);
  return u.h;
}

__device__ __forceinline__ float pe_val(int k, float x0, float x1, float x2) {
  float r;
  if (k >= 63) r = 0.f;
  else if (k < 3) r = (k == 0) ? x0 : (k == 1 ? x1 : x2);
  else {
    int kk = k - 3;
    int f = kk / 6;
    int rem = kk - 6 * f;
    int s = (rem >= 3) ? 1 : 0;
    int i3 = rem - 3 * s;
    float xi = (i3 == 0) ? x0 : (i3 == 1 ? x1 : x2);
    float arg = xi * (float)(1 << f);
    float nn = rintf(arg * 0.15915494309189535f);
    float rr = fmaf(nn, -6.28318548202514648f, arg);
    rr = fmaf(nn, 1.7484555e-7f, rr);
    r = s ? __cosf(rr) : __sinf(rr);
  }
  return r;
}

// ---- standalone positional encoding: E[131072][64] f16, 4 threads/point ----
__global__ __launch_bounds__(256) void pe(const float* __restrict__ coords,
                                          _Float16* __restrict__ eg) {
  int id = blockIdx.x * 256 + threadIdx.x;   // 524288 threads
  int m = id >> 2, s = id & 3;
  const float* cp = coords + (size_t)m * 3;
  float x0 = cp[0], x1 = cp[1], x2 = cp[2];
  int kh = s * 16;
#pragma unroll
  for (int i = 0; i < 2; ++i) {
    float v[8];
#pragma unroll
    for (int u = 0; u < 8; ++u) v[u] = pe_val(kh + i * 8 + u, x0, x1, x2);
    half8 ev;
#pragma unroll
    for (int u = 0; u < 4; ++u) {
      fp16x2 p = __builtin_amdgcn_cvt_pkrtz(v[2 * u], v[2 * u + 1]);
      ev[2 * u] = (_Float16)p[0]; ev[2 * u + 1] = (_Float16)p[1];
    }
    *(half8*)(eg + (size_t)m * 64 + kh + i * 8) = ev;
  }
}

// ================= main kernel, E from global (primary path) =================
__global__ __launch_bounds__(256, 2) void mlp_main_g(
    const _Float16* __restrict__ eg,
    const _Float16* __restrict__ W0sw,
    const _Float16* __restrict__ W1sw,
    const _Float16* __restrict__ W2sw,
    const float* __restrict__ b0, const float* __restrict__ b1,
    const float* __restrict__ b2,
    const float* __restrict__ Wocc, const float* __restrict__ bocc,
    const float* __restrict__ Wc, const float* __restrict__ bc,
    float* __restrict__ out) {
  __shared__ _Float16 actX[M_PB * AST];   // h -> t1 (one buffer, barriered)
  __shared__ float occ_s[4][M_PB];

  const int t = threadIdx.x;
  const int w = t >> 6;          // wave = neuron slice [64w,64w+64) = part id
  const int l = t & 63;
  const int c = l & 15;
  const int q = l >> 4;
  const int sx = c & 7;          // swizzle key for rows tm*16+c
  const int m0 = blockIdx.x * M_PB;

  // ---- E fragments: global -> registers, issued first (latency hidden) ----
  half8 e0[8], e1[8];
  {
    const _Float16* ep = eg + (size_t)(m0 + c) * 64 + q * 8;
#pragma unroll
    for (int tm = 0; tm < 8; ++tm) {
      e0[tm] = *(const half8*)(ep + tm * 1024);        // kb=0: k 0..31 slice
      e1[tm] = *(const half8*)(ep + tm * 1024 + 32);   // kb=1: k 32..63 slice
    }
  }
  // ---- layer-0 weight fragments ----
  half8 a0[4], a1[4];
  {
    const _Float16* wb = W0sw + (size_t)w * 4096 + l * 8;
#pragma unroll
    for (int tn = 0; tn < 4; ++tn) {
      a0[tn] = *(const half8*)(wb + tn * 512);
      a1[tn] = *(const half8*)(wb + 2048 + tn * 512);
    }
  }

  float4_t acc[4][8];
  const _Float16* rp = actX + c * AST;   // row base for B-reads (row = tm*16+c)

  // ---- layer 0: h = E @ W0 + b0 (no relu), E register-direct ----
  {
#pragma unroll
    for (int tn = 0; tn < 4; ++tn) {
      float4_t bz = *(const float4_t*)(b0 + 64 * w + tn * 16 + q * 4);
#pragma unroll
      for (int tm = 0; tm < 8; ++tm) acc[tn][tm] = bz;
    }
#pragma unroll
    for (int tn = 0; tn < 4; ++tn)
#pragma unroll
      for (int tm = 0; tm < 8; ++tm)
        acc[tn][tm] = __builtin_amdgcn_mfma_f32_16x16x32_f16(
            a0[tn], e0[tm], acc[tn][tm], 0, 0, 0);
#pragma unroll
    for (int tn = 0; tn < 4; ++tn)
#pragma unroll
      for (int tm = 0; tm < 8; ++tm)
        acc[tn][tm] = __builtin_amdgcn_mfma_f32_16x16x32_f16(
            a1[tn], e1[tm], acc[tn][tm], 0, 0, 0);
  }
  // store h: waves write disjoint chunk ranges -> no barrier needed before
#pragma unroll
  for (int tn = 0; tn < 4; ++tn) {
    const int sc = ((8 * w + 2 * tn + (q >> 1)) ^ sx) * 8 + (q & 1) * 4;
#pragma unroll
    for (int tm = 0; tm < 8; ++tm) {
      float4_t v = acc[tn][tm];
      *(half4_t*)&actX[(tm * 16 + c) * AST + sc] = pack4(v[0], v[1], v[2], v[3]);
    }
  }
  __syncthreads();                                   // (A) h ready

  // ---- layer 1 (+ part head): masked kb pair FIRST, snapshot after j==1 ----
  {
    const _Float16* wb = W1sw + (size_t)w * 16384 + l * 8;
    const int w2 = 2 * w;
    float bcw = bc[w];
#pragma unroll
    for (int tn = 0; tn < 4; ++tn) {
      float4_t bz = *(const float4_t*)(b1 + 64 * w + tn * 16 + q * 4);
#pragma unroll
      for (int tm = 0; tm < 8; ++tm) acc[tn][tm] = bz;
    }
    auto kbof = [&](int j) {
      return (j < 2) ? (w2 + j) : ((j - 2) + ((j - 2) >= w2 ? 2 : 0));
    };
    half8 A[3][4];
#pragma unroll
    for (int p = 0; p < 3; ++p) {
      const _Float16* pa = wb + kbof(p) * 2048;
#pragma unroll
      for (int tn = 0; tn < 4; ++tn) A[p][tn] = *(const half8*)(pa + tn * 512);
    }
#pragma unroll
    for (int j = 0; j < 8; ++j) {
      const int kb = kbof(j);
      const int cx = ((kb * 4 + q) ^ sx) << 3;
      half8 b[8];
#pragma unroll
      for (int tm = 0; tm < 8; ++tm) b[tm] = *(const half8*)(rp + tm * 16 * AST + cx);
      // consume A[j%3] BEFORE the lookahead-3 prefetch overwrites it
#pragma unroll
      for (int tn = 0; tn < 4; ++tn)
#pragma unroll
        for (int tm = 0; tm < 8; ++tm)
          acc[tn][tm] = __builtin_amdgcn_mfma_f32_16x16x32_f16(
              A[j % 3][tn], b[tm], acc[tn][tm], 0, 0, 0);
      if (j == 1) {
        float pcls[8] = {0.f, 0.f, 0.f, 0.f, 0.f, 0.f, 0.f, 0.f};
#pragma unroll
        for (int tn = 0; tn < 4; ++tn) {
          float4_t wcv = *(const float4_t*)(Wc + 256 * w + 64 * w + tn * 16 + q * 4);
#pragma unroll
          for (int tm = 0; tm < 8; ++tm) {
            float4_t v = acc[tn][tm];
#pragma unroll
            for (int r = 0; r < 4; ++r) pcls[tm] += fmaxf(v[r], 0.f) * wcv[r];
          }
        }
#pragma unroll
        for (int tm = 0; tm < 8; ++tm) {
          float s = pcls[tm];
          s += __shfl_xor(s, 16, 64);
          s += __shfl_xor(s, 32, 64);
          if (l < 16)
            out[(size_t)NPTS + (size_t)(m0 + tm * 16 + c) * 4 + w] = s + bcw;
        }
      }
      if (j + 3 < 8) {   // prefetch AFTER use
        const _Float16* pa = wb + kbof(j + 3) * 2048;
#pragma unroll
        for (int tn = 0; tn < 4; ++tn) A[j % 3][tn] = *(const half8*)(pa + tn * 512);
      }
    }
  }
  __syncthreads();                                   // (B) all h reads done
#pragma unroll
  for (int tn = 0; tn < 4; ++tn) {
    const int sc = ((8 * w + 2 * tn + (q >> 1)) ^ sx) * 8 + (q & 1) * 4;
#pragma unroll
    for (int tm = 0; tm < 8; ++tm) {
      float4_t v = acc[tn][tm];
      *(half4_t*)&actX[(tm * 16 + c) * AST + sc] =
          pack4(fmaxf(v[0], 0.f), fmaxf(v[1], 0.f), fmaxf(v[2], 0.f), fmaxf(v[3], 0.f));
    }
  }
  __syncthreads();                                   // (C) t1 ready

  // ---- layer 2 + occ head ----
  {
    const _Float16* wb = W2sw + (size_t)w * 16384 + l * 8;
#pragma unroll
    for (int tn = 0; tn < 4; ++tn) {
      float4_t bz = *(const float4_t*)(b2 + 64 * w + tn * 16 + q * 4);
#pragma unroll
      for (int tm = 0; tm < 8; ++tm) acc[tn][tm] = bz;
    }
    half8 A[3][4];
#pragma unroll
    for (int p = 0; p < 3; ++p)
#pragma unroll
      for (int tn = 0; tn < 4; ++tn)
        A[p][tn] = *(const half8*)(wb + p * 2048 + tn * 512);
#pragma unroll
    for (int kb = 0; kb < 8; ++kb) {
      const int cx = ((kb * 4 + q) ^ sx) << 3;
      half8 b[8];
#pragma unroll
      for (int tm = 0; tm < 8; ++tm) b[tm] = *(const half8*)(rp + tm * 16 * AST + cx);
#pragma unroll
      for (int tn = 0; tn < 4; ++tn)
#pragma unroll
        for (int tm = 0; tm < 8; ++tm)
          acc[tn][tm] = __builtin_amdgcn_mfma_f32_16x16x32_f16(
              A[kb % 3][tn], b[tm], acc[tn][tm], 0, 0, 0);
      if (kb + 3 < 8) {
#pragma unroll
        for (int tn = 0; tn < 4; ++tn)
          A[kb % 3][tn] = *(const half8*)(wb + (kb + 3) * 2048 + tn * 512);
      }
    }
    float pocc[8] = {0.f, 0.f, 0.f, 0.f, 0.f, 0.f, 0.f, 0.f};
#pragma unroll
    for (int tn = 0; tn < 4; ++tn) {
      float4_t wov = *(const float4_t*)(Wocc + 64 * w + tn * 16 + q * 4);
#pragma unroll
      for (int tm = 0; tm < 8; ++tm) {
        float4_t v = acc[tn][tm];
#pragma unroll
        for (int r = 0; r < 4; ++r) pocc[tm] += fmaxf(v[r], 0.f) * wov[r];
      }
    }
#pragma unroll
    for (int tm = 0; tm < 8; ++tm) {
      float s = pocc[tm];
      s += __shfl_xor(s, 16, 64);
      s += __shfl_xor(s, 32, 64);
      if (l < 16) occ_s[w][tm * 16 + c] = s;
    }
  }
  __syncthreads();                                   // (D) occ partials ready
  if (t < M_PB) {
    out[m0 + t] = occ_s[0][t] + occ_s[1][t] + occ_s[2][t] + occ_s[3][t] + bocc[0];
  }
}

// ============ fallback: r11 verbatim (fused PE, 6 barriers) ============
__global__ __launch_bounds__(256, 2) void mlp_main_l(
    const float* __restrict__ coords,
    const _Float16* __restrict__ W0sw,
    const _Float16* __restrict__ W1sw,
    const _Float16* __restrict__ W2sw,
    const float* __restrict__ b0, const float* __restrict__ b1,
    const float* __restrict__ b2,
    const float* __restrict__ Wocc, const float* __restrict__ bocc,
    const float* __restrict__ Wc, const float* __restrict__ bc,
    float* __restrict__ out) {
  __shared__ _Float16 actX[M_PB * AST];
  __shared__ float occ_s[4][M_PB];

  const int t = threadIdx.x;
  const int w = t >> 6;
  const int l = t & 63;
  const int c = l & 15;
  const int q = l >> 4;
  const int sx = c & 7;
  const int m0 = blockIdx.x * M_PB;

  half8 a0[4], a1[4];
  {
    const _Float16* wb = W0sw + (size_t)w * 4096 + l * 8;
#pragma unroll
    for (int tn = 0; tn < 4; ++tn) {
      a0[tn] = *(const half8*)(wb + tn * 512);
      a1[tn] = *(const half8*)(wb + 2048 + tn * 512);
    }
  }
  {
    int m = t & 127, kh = (t >> 7) * 32;
    const int cb = (t >> 7) * 4;
    const int sm = m & 7;
    const float* cp = coords + (size_t)(m0 + m) * 3;
    float x0 = cp[0], x1 = cp[1], x2 = cp[2];
#pragma unroll
    for (int i = 0; i < 4; ++i) {
      float v[8];
#pragma unroll
      for (int u = 0; u < 8; ++u) v[u] = pe_val(kh + i * 8 + u, x0, x1, x2);
      half8 ev;
#pragma unroll
      for (int u = 0; u < 4; ++u) {
        fp16x2 p = __builtin_amdgcn_cvt_pkrtz(v[2 * u], v[2 * u + 1]);
        ev[2 * u] = (_Float16)p[0]; ev[2 * u + 1] = (_Float16)p[1];
      }
      *(half8*)&actX[m * AST + (((cb + i) ^ sm) << 3)] = ev;
    }
  }
  __syncthreads();

  float4_t acc[4][8];
  const _Float16* rp = actX + c * AST;

  {
#pragma unroll
    for (int tn = 0; tn < 4; ++tn) {
      float4_t bz = *(const float4_t*)(b0 + 64 * w + tn * 16 + q * 4);
#pragma unroll
      for (int tm = 0; tm < 8; ++tm) acc[tn][tm] = bz;
    }
#pragma unroll
    for (int kb = 0; kb < 2; ++kb) {
      const int cx = ((kb * 4 + q) ^ sx) << 3;
      half8 b[8];
#pragma unroll
      for (int tm = 0; tm < 8; ++tm) b[tm] = *(const half8*)(rp + tm * 16 * AST + cx);
#pragma unroll
      for (int tn = 0; tn < 4; ++tn)
#pragma unroll
        for (int tm = 0; tm < 8; ++tm)
          acc[tn][tm] = __builtin_amdgcn_mfma_f32_16x16x32_f16(
              kb ? a1[tn] : a0[tn], b[tm], acc[tn][tm], 0, 0, 0);
    }
  }
  __syncthreads();
#pragma unroll
  for (int tn = 0; tn < 4; ++tn) {
    const int sc = ((8 * w + 2 * tn + (q >> 1)) ^ sx) * 8 + (q & 1) * 4;
#pragma unroll
    for (int tm = 0; tm < 8; ++tm) {
      float4_t v = acc[tn][tm];
      *(half4_t*)&actX[(tm * 16 + c) * AST + sc] = pack4(v[0], v[1], v[2], v[3]);
    }
  }
  __syncthreads();

  {
    const _Float16* wb = W1sw + (size_t)w * 16384 + l * 8;
    const int w2 = 2 * w;
    float bcw = bc[w];
#pragma unroll
    for (int tn = 0; tn < 4; ++tn) {
      float4_t bz = *(const float4_t*)(b1 + 64 * w + tn * 16 + q * 4);
#pragma unroll
      for (int tm = 0; tm < 8; ++tm) acc[tn][tm] = bz;
    }
    auto kbof = [&](int j) {
      return (j < 2) ? (w2 + j) : ((j - 2) + ((j - 2) >= w2 ? 2 : 0));
    };
    half8 A[3][4];
#pragma unroll
    for (int p = 0; p < 3; ++p) {
      const _Float16* pa = wb + kbof(p) * 2048;
#pragma unroll
      for (int tn = 0; tn < 4; ++tn) A[p][tn] = *(const half8*)(pa + tn * 512);
    }
#pragma unroll
    for (int j = 0; j < 8; ++j) {
      const int kb = kbof(j);
      const int cx = ((kb * 4 + q) ^ sx) << 3;
      half8 b[8];
#pragma unroll
      for (int tm = 0; tm < 8; ++tm) b[tm] = *(const half8*)(rp + tm * 16 * AST + cx);
#pragma unroll
      for (int tn = 0; tn < 4; ++tn)
#pragma unroll
        for (int tm = 0; tm < 8; ++tm)
          acc[tn][tm] = __builtin_amdgcn_mfma_f32_16x16x32_f16(
              A[j % 3][tn], b[tm], acc[tn][tm], 0, 0, 0);
      if (j == 1) {
        float pcls[8] = {0.f, 0.f, 0.f, 0.f, 0.f, 0.f, 0.f, 0.f};
#pragma unroll
        for (int tn = 0; tn < 4; ++tn) {
          float4_t wcv = *(const float4_t*)(Wc + 256 * w + 64 * w + tn * 16 + q * 4);
#pragma unroll
          for (int tm = 0; tm < 8; ++tm) {
            float4_t v = acc[tn][tm];
#pragma unroll
            for (int r = 0; r < 4; ++r) pcls[tm] += fmaxf(v[r], 0.f) * wcv[r];
          }
        }
#pragma unroll
        for (int tm = 0; tm < 8; ++tm) {
          float s = pcls[tm];
          s += __shfl_xor(s, 16, 64);
          s += __shfl_xor(s, 32, 64);
          if (l < 16)
            out[(size_t)NPTS + (size_t)(m0 + tm * 16 + c) * 4 + w] = s + bcw;
        }
      }
      if (j + 3 < 8) {
        const _Float16* pa = wb + kbof(j + 3) * 2048;
#pragma unroll
        for (int tn = 0; tn < 4; ++tn) A[j % 3][tn] = *(const half8*)(pa + tn * 512);
      }
    }
  }
  __syncthreads();
#pragma unroll
  for (int tn = 0; tn < 4; ++tn) {
    const int sc = ((8 * w + 2 * tn + (q >> 1)) ^ sx) * 8 + (q & 1) * 4;
#pragma unroll
    for (int tm = 0; tm < 8; ++tm) {
      float4_t v = acc[tn][tm];
      *(half4_t*)&actX[(tm * 16 + c) * AST + sc] =
          pack4(fmaxf(v[0], 0.f), fmaxf(v[1], 0.f), fmaxf(v[2], 0.f), fmaxf(v[3], 0.f));
    }
  }
  __syncthreads();

  {
    const _Float16* wb = W2sw + (size_t)w * 16384 + l * 8;
#pragma unroll
    for (int tn = 0; tn < 4; ++tn) {
      float4_t bz = *(const float4_t*)(b2 + 64 * w + tn * 16 + q * 4);
#pragma unroll
      for (int tm = 0; tm < 8; ++tm) acc[tn][tm] = bz;
    }
    half8 A[3][4];
#pragma unroll
    for (int p = 0; p < 3; ++p)
#pragma unroll
      for (int tn = 0; tn < 4; ++tn)
        A[p][tn] = *(const half8*)(wb + p * 2048 + tn * 512);
#pragma unroll
    for (int kb = 0; kb < 8; ++kb) {
      const int cx = ((kb * 4 + q) ^ sx) << 3;
      half8 b[8];
#pragma unroll
      for (int tm = 0; tm < 8; ++tm) b[tm] = *(const half8*)(rp + tm * 16 * AST + cx);
#pragma unroll
      for (int tn = 0; tn < 4; ++tn)
#pragma unroll
        for (int tm = 0; tm < 8; ++tm)
          acc[tn][tm] = __builtin_amdgcn_mfma_f32_16x16x32_f16(
              A[kb % 3][tn], b[tm], acc[tn][tm], 0, 0, 0);
      if (kb + 3 < 8) {
#pragma unroll
        for (int tn = 0; tn < 4; ++tn)
          A[kb % 3][tn] = *(const half8*)(wb + (kb + 3) * 2048 + tn * 512);
      }
    }
    float pocc[8] = {0.f, 0.f, 0.f, 0.f, 0.f, 0.f, 0.f, 0.f};
#pragma unroll
    for (int tn = 0; tn < 4; ++tn) {
      float4_t wov = *(const float4_t*)(Wocc + 64 * w + tn * 16 + q * 4);
#pragma unroll
      for (int tm = 0; tm < 8; ++tm) {
        float4_t v = acc[tn][tm];
#pragma unroll
        for (int r = 0; r < 4; ++r) pocc[tm] += fmaxf(v[r], 0.f) * wov[r];
      }
    }
#pragma unroll
    for (int tm = 0; tm < 8; ++tm) {
      float s = pocc[tm];
      s += __shfl_xor(s, 16, 64);
      s += __shfl_xor(s, 32, 64);
      if (l < 16) occ_s[w][tm * 16 + c] = s;
    }
  }
  __syncthreads();
  if (t < M_PB) {
    out[m0 + t] = occ_s[0][t] + occ_s[1][t] + occ_s[2][t] + occ_s[3][t] + bocc[0];
  }
}

extern "C" void kernel_launch(void* const* d_in, const int* in_sizes, int n_in,
                              void* d_out, int out_size, void* d_ws, size_t ws_size,
                              hipStream_t stream) {
  const float* coords = (const float*)d_in[0];
  const float* W0   = (const float*)d_in[1];
  const float* b0   = (const float*)d_in[2];
  const float* W1   = (const float*)d_in[3];
  const float* b1   = (const float*)d_in[4];
  const float* W2   = (const float*)d_in[5];
  const float* b2   = (const float*)d_in[6];
  const float* Wocc = (const float*)d_in[7];
  const float* bocc = (const float*)d_in[8];
  const float* Wc   = (const float*)d_in[9];
  const float* bc   = (const float*)d_in[10];
  float* out = (float*)d_out;

  _Float16* ws = (_Float16*)d_ws;       // W0sw[16384] | W1sw[65536] | W2sw[65536]
  _Float16* W0sw = ws;
  _Float16* W1sw = ws + 16384;
  _Float16* W2sw = ws + 81920;

  const size_t wbytes = 147456 * sizeof(_Float16);            // 294912
  const size_t ebytes = (size_t)NPTS * 64 * sizeof(_Float16); // 16.8MB

  prep<<<576, 256, 0, stream>>>(W0, W1, W2, ws);

  if (ws_size >= wbytes + ebytes) {
    _Float16* eg = (_Float16*)((char*)d_ws + wbytes);
    pe<<<(NPTS * 4) / 256, 256, 0, stream>>>(coords, eg);
    mlp_main_g<<<NPTS / M_PB, 256, 0, stream>>>(eg, W0sw, W1sw, W2sw,
                                                b0, b1, b2, Wocc, bocc, Wc, bc, out);
  } else {
    mlp_main_l<<<NPTS / M_PB, 256, 0, stream>>>(coords, W0sw, W1sw, W2sw,
                                                b0, b1, b2, Wocc, bocc, Wc, bc, out);
  }
}

// Round 10
// 117.018 us; speedup vs baseline: 1.5375x; 1.0701x over previous
//
#include <hip/hip_runtime.h>

// MLP3D fused, MI355X gfx950 — round 17: 32x32x16 MFMA shape.
// Evidence chain: r16 removed PE (+9us VALU) and 2 barriers -> wall unchanged
// (48.5 ≈ r11 48.9); r14 phase-offset null; r9 3-waves/SIMD worse. The wall
// is pinned by the per-wave MFMA issue stream: 576 blocking mfma_16x16x32
// (19.4 cyc each) per wave. r17 halves the event count: 288 mfma_32x32x16
// (33.8 cyc, better rate: 2382 vs 2075 TF ubench) -> -14% matrix-blocked
// time and 2x fewer issue events. acc = 2x4 tiles x f32x16 = 128 AGPR
// (same); A-rotation 24 regs (was 48), b-frags 16 (was 32).
// Layouts (verified m74/m101): C/D col=lane&31(point), row=(r&3)+8(r>>2)+
// 4(lane>>5) (neuron); A/B lane holds 8 halves k=(l>>5)*8+j at n/pt=l&31.
// Same XOR chunk-swizzle (chunk ^ row&7, 8-half chunks). Masked-first L1:
// ksteps {4w..4w+3} first, class-head snapshot after j==3.
// Single fused kernel (PE back in; r16's pe-split cost +10us bench at equal
// mlp time — bench has ~65us fixed overhead, so minimize dispatch count).

#define NPTS 131072
#define M_PB 128
#define AST 256

typedef _Float16 half8   __attribute__((ext_vector_type(8)));
typedef _Float16 half4_t __attribute__((ext_vector_type(4)));
typedef __fp16   fp16x2  __attribute__((ext_vector_type(2)));
typedef float    float4_t __attribute__((ext_vector_type(4)));
typedef float    f32x16  __attribute__((ext_vector_type(16)));

// ---- prep: W (f32 [K][256]) -> f16 32x32x16 A-fragment layout ----
// dst[(((s*KS + ks)*2 + tn)*64 + l)*8 + j] =
//   W[ks*16 + (l>>5)*8 + j][s*64 + tn*32 + (l&31)]
__global__ void prep(const float* __restrict__ W0, const float* __restrict__ W1,
                     const float* __restrict__ W2, _Float16* __restrict__ ws) {
  int id = blockIdx.x * 256 + threadIdx.x;   // 147456 total
  _Float16 v;
  if (id < 16384) {            // W0sw: 4 slices x 4 ks x 2 tn x 512
    int e = id, j = e & 7, l = (e >> 3) & 63, tn = (e >> 9) & 1, ks = (e >> 10) & 3, s = e >> 12;
    int k = ks * 16 + (l >> 5) * 8 + j, n = s * 64 + tn * 32 + (l & 31);
    v = (k < 63) ? (_Float16)W0[k * 256 + n] : (_Float16)0.f;
  } else if (id < 81920) {     // W1sw: 4 x 16 x 2 x 512
    int e = id - 16384, j = e & 7, l = (e >> 3) & 63, tn = (e >> 9) & 1, ks = (e >> 10) & 15, s = e >> 14;
    int k = ks * 16 + (l >> 5) * 8 + j, n = s * 64 + tn * 32 + (l & 31);
    v = (_Float16)W1[k * 256 + n];
  } else {                     // W2sw
    int e = id - 81920, j = e & 7, l = (e >> 3) & 63, tn = (e >> 9) & 1, ks = (e >> 10) & 15, s = e >> 14;
    int k = ks * 16 + (l >> 5) * 8 + j, n = s * 64 + tn * 32 + (l & 31);
    v = (_Float16)W2[k * 256 + n];
  }
  ws[id] = v;
}

__device__ __forceinline__ half4_t pack4(float a, float b, float cc, float d) {
  fp16x2 p0 = __builtin_amdgcn_cvt_pkrtz(a, b);
  fp16x2 p1 = __builtin_amdgcn_cvt_pkrtz(cc, d);
  half4_t h;
  h[0] = (_Float16)p0[0]; h[1] = (_Float16)p0[1];
  h[2] = (_Float16)p1[0]; h[3] = (_Float16)p1[1];
  return h;
}

__device__ __forceinline__ float pe_val(int k, float x0, float x1, float x2) {
  float r;
  if (k >= 63) r = 0.f;
  else if (k < 3) r = (k == 0) ? x0 : (k == 1 ? x1 : x2);
  else {
    int kk = k - 3;
    int f = kk / 6;
    int rem = kk - 6 * f;
    int s = (rem >= 3) ? 1 : 0;
    int i3 = rem - 3 * s;
    float xi = (i3 == 0) ? x0 : (i3 == 1 ? x1 : x2);
    float arg = xi * (float)(1 << f);
    float nn = rintf(arg * 0.15915494309189535f);
    float rr = fmaf(nn, -6.28318548202514648f, arg);
    rr = fmaf(nn, 1.7484555e-7f, rr);
    r = s ? __cosf(rr) : __sinf(rr);
  }
  return r;
}

__global__ __launch_bounds__(256, 2) void mlp_main(
    const float* __restrict__ coords,
    const _Float16* __restrict__ W0sw,
    const _Float16* __restrict__ W1sw,
    const _Float16* __restrict__ W2sw,
    const float* __restrict__ b0, const float* __restrict__ b1,
    const float* __restrict__ b2,
    const float* __restrict__ Wocc, const float* __restrict__ bocc,
    const float* __restrict__ Wc, const float* __restrict__ bc,
    float* __restrict__ out) {
  __shared__ _Float16 actX[M_PB * AST];   // E -> h -> t1 (one buffer, barriered)
  __shared__ float occ_s[4][M_PB];

  const int t = threadIdx.x;
  const int w = t >> 6;          // wave = neuron slice [64w,64w+64) = part id
  const int l = t & 63;
  const int p31 = l & 31;        // point-in-tile (C/D col; B free dim)
  const int hi = l >> 5;         // lane half: k-group and neuron-row offset
  const int sx = l & 7;          // swizzle key: rows are ≡ p31 (mod 32)
  const int m0 = blockIdx.x * M_PB;

  // ---- positional encoding: 2 threads/point, 32 k-values each ----
  {
    int m = t & 127, kh = (t >> 7) * 32;
    const int cb = (t >> 7) * 4;
    const int sm = m & 7;
    const float* cp = coords + (size_t)(m0 + m) * 3;
    float x0 = cp[0], x1 = cp[1], x2 = cp[2];
#pragma unroll
    for (int i = 0; i < 4; ++i) {
      float v[8];
#pragma unroll
      for (int u = 0; u < 8; ++u) v[u] = pe_val(kh + i * 8 + u, x0, x1, x2);
      half8 ev;
#pragma unroll
      for (int u = 0; u < 4; ++u) {
        fp16x2 p = __builtin_amdgcn_cvt_pkrtz(v[2 * u], v[2 * u + 1]);
        ev[2 * u] = (_Float16)p[0]; ev[2 * u + 1] = (_Float16)p[1];
      }
      *(half8*)&actX[m * AST + (((cb + i) ^ sm) << 3)] = ev;
    }
  }
  __syncthreads();                                   // (1) E ready

  f32x16 acc[2][4];
  const _Float16* rp = actX + p31 * AST;   // row base (row = tp*32 + p31)

  // ---- layer 0: h = E @ W0 + b0 (no relu), K=64 (4 ksteps, A upfront) ----
  {
    const _Float16* wb = W0sw + (size_t)w * 4096 + l * 8;  // slice stride 4*2*512
    half8 a[4][2];
#pragma unroll
    for (int ks = 0; ks < 4; ++ks)
#pragma unroll
      for (int tn = 0; tn < 2; ++tn)
        a[ks][tn] = *(const half8*)(wb + (ks * 2 + tn) * 512);
#pragma unroll
    for (int tn = 0; tn < 2; ++tn) {
      float4_t bz0 = *(const float4_t*)(b0 + 64 * w + 32 * tn + 4 * hi);
      float4_t bz1 = *(const float4_t*)(b0 + 64 * w + 32 * tn + 8 + 4 * hi);
      float4_t bz2 = *(const float4_t*)(b0 + 64 * w + 32 * tn + 16 + 4 * hi);
      float4_t bz3 = *(const float4_t*)(b0 + 64 * w + 32 * tn + 24 + 4 * hi);
#pragma unroll
      for (int tp = 0; tp < 4; ++tp) {
#pragma unroll
        for (int e = 0; e < 4; ++e) {
          acc[tn][tp][e] = bz0[e];
          acc[tn][tp][4 + e] = bz1[e];
          acc[tn][tp][8 + e] = bz2[e];
          acc[tn][tp][12 + e] = bz3[e];
        }
      }
    }
#pragma unroll
    for (int ks = 0; ks < 4; ++ks) {
      const int cx = ((ks * 2 + hi) ^ sx) << 3;
      half8 b[4];
#pragma unroll
      for (int tp = 0; tp < 4; ++tp) b[tp] = *(const half8*)(rp + tp * 32 * AST + cx);
#pragma unroll
      for (int tn = 0; tn < 2; ++tn)
#pragma unroll
        for (int tp = 0; tp < 4; ++tp)
          acc[tn][tp] = __builtin_amdgcn_mfma_f32_32x32x16_f16(
              a[ks][tn], b[tp], acc[tn][tp], 0, 0, 0);
    }
  }
  __syncthreads();                                   // (2) all E reads done
  // store h: lane covers point tp*32+p31, neurons 64w+32tn+8bc+(0..3)+4hi
#pragma unroll
  for (int tn = 0; tn < 2; ++tn)
#pragma unroll
    for (int bc = 0; bc < 4; ++bc) {
      const int sc = ((8 * w + 4 * tn + bc) ^ sx) * 8 + 4 * hi;
#pragma unroll
      for (int tp = 0; tp < 4; ++tp) {
        *(half4_t*)&actX[(tp * 32 + p31) * AST + sc] =
            pack4(acc[tn][tp][4 * bc], acc[tn][tp][4 * bc + 1],
                  acc[tn][tp][4 * bc + 2], acc[tn][tp][4 * bc + 3]);
      }
    }
  __syncthreads();                                   // (3) h ready

  // ---- layer 1 (+ part head): masked ksteps {4w..4w+3} FIRST, snapshot j==3 ----
  {
    const _Float16* wb = W1sw + (size_t)w * 16384 + l * 8;  // slice 16*2*512
    const int w4 = 4 * w;
    float bcw = bc[w];
#pragma unroll
    for (int tn = 0; tn < 2; ++tn) {
      float4_t bz0 = *(const float4_t*)(b1 + 64 * w + 32 * tn + 4 * hi);
      float4_t bz1 = *(const float4_t*)(b1 + 64 * w + 32 * tn + 8 + 4 * hi);
      float4_t bz2 = *(const float4_t*)(b1 + 64 * w + 32 * tn + 16 + 4 * hi);
      float4_t bz3 = *(const float4_t*)(b1 + 64 * w + 32 * tn + 24 + 4 * hi);
#pragma unroll
      for (int tp = 0; tp < 4; ++tp) {
#pragma unroll
        for (int e = 0; e < 4; ++e) {
          acc[tn][tp][e] = bz0[e];
          acc[tn][tp][4 + e] = bz1[e];
          acc[tn][tp][8 + e] = bz2[e];
          acc[tn][tp][12 + e] = bz3[e];
        }
      }
    }
    auto ksof = [&](int j) {
      return (j < 4) ? (w4 + j) : ((j - 4) + ((j - 4) >= w4 ? 4 : 0));
    };
    half8 A[3][2];
#pragma unroll
    for (int p = 0; p < 3; ++p) {
      const _Float16* pa = wb + ksof(p) * 1024;
#pragma unroll
      for (int tn = 0; tn < 2; ++tn) A[p][tn] = *(const half8*)(pa + tn * 512);
    }
#pragma unroll
    for (int j = 0; j < 16; ++j) {
      const int ks = ksof(j);
      const int cx = ((ks * 2 + hi) ^ sx) << 3;
      half8 b[4];
#pragma unroll
      for (int tp = 0; tp < 4; ++tp) b[tp] = *(const half8*)(rp + tp * 32 * AST + cx);
      // consume A[j%3] BEFORE the lookahead-3 prefetch overwrites it
#pragma unroll
      for (int tn = 0; tn < 2; ++tn)
#pragma unroll
        for (int tp = 0; tp < 4; ++tp)
          acc[tn][tp] = __builtin_amdgcn_mfma_f32_32x32x16_f16(
              A[j % 3][tn], b[tp], acc[tn][tp], 0, 0, 0);
      if (j == 3) {
        // snapshot: acc = b1 + (x*mask_w)@W1-slice -> class head for part w
        float pcls[4] = {0.f, 0.f, 0.f, 0.f};
#pragma unroll
        for (int tn = 0; tn < 2; ++tn) {
          float4_t w0v = *(const float4_t*)(Wc + 256 * w + 64 * w + 32 * tn + 4 * hi);
          float4_t w1v = *(const float4_t*)(Wc + 256 * w + 64 * w + 32 * tn + 8 + 4 * hi);
          float4_t w2v = *(const float4_t*)(Wc + 256 * w + 64 * w + 32 * tn + 16 + 4 * hi);
          float4_t w3v = *(const float4_t*)(Wc + 256 * w + 64 * w + 32 * tn + 24 + 4 * hi);
#pragma unroll
          for (int tp = 0; tp < 4; ++tp) {
#pragma unroll
            for (int e = 0; e < 4; ++e) {
              pcls[tp] += fmaxf(acc[tn][tp][e], 0.f) * w0v[e];
              pcls[tp] += fmaxf(acc[tn][tp][4 + e], 0.f) * w1v[e];
              pcls[tp] += fmaxf(acc[tn][tp][8 + e], 0.f) * w2v[e];
              pcls[tp] += fmaxf(acc[tn][tp][12 + e], 0.f) * w3v[e];
            }
          }
        }
#pragma unroll
        for (int tp = 0; tp < 4; ++tp) {
          float s = pcls[tp];
          s += __shfl_xor(s, 32, 64);   // add complementary neuron half
          if (l < 32)
            out[(size_t)NPTS + (size_t)(m0 + tp * 32 + p31) * 4 + w] = s + bcw;
        }
      }
      if (j + 3 < 16) {   // prefetch AFTER use
        const _Float16* pa = wb + ksof(j + 3) * 1024;
#pragma unroll
        for (int tn = 0; tn < 2; ++tn) A[j % 3][tn] = *(const half8*)(pa + tn * 512);
      }
    }
  }
  __syncthreads();                                   // (4) all h reads done
#pragma unroll
  for (int tn = 0; tn < 2; ++tn)
#pragma unroll
    for (int bc = 0; bc < 4; ++bc) {
      const int sc = ((8 * w + 4 * tn + bc) ^ sx) * 8 + 4 * hi;
#pragma unroll
      for (int tp = 0; tp < 4; ++tp) {
        *(half4_t*)&actX[(tp * 32 + p31) * AST + sc] =
            pack4(fmaxf(acc[tn][tp][4 * bc], 0.f), fmaxf(acc[tn][tp][4 * bc + 1], 0.f),
                  fmaxf(acc[tn][tp][4 * bc + 2], 0.f), fmaxf(acc[tn][tp][4 * bc + 3], 0.f));
      }
    }
  __syncthreads();                                   // (5) t1 ready

  // ---- layer 2 + occ head ----
  {
    const _Float16* wb = W2sw + (size_t)w * 16384 + l * 8;
#pragma unroll
    for (int tn = 0; tn < 2; ++tn) {
      float4_t bz0 = *(const float4_t*)(b2 + 64 * w + 32 * tn + 4 * hi);
      float4_t bz1 = *(const float4_t*)(b2 + 64 * w + 32 * tn + 8 + 4 * hi);
      float4_t bz2 = *(const float4_t*)(b2 + 64 * w + 32 * tn + 16 + 4 * hi);
      float4_t bz3 = *(const float4_t*)(b2 + 64 * w + 32 * tn + 24 + 4 * hi);
#pragma unroll
      for (int tp = 0; tp < 4; ++tp) {
#pragma unroll
        for (int e = 0; e < 4; ++e) {
          acc[tn][tp][e] = bz0[e];
          acc[tn][tp][4 + e] = bz1[e];
          acc[tn][tp][8 + e] = bz2[e];
          acc[tn][tp][12 + e] = bz3[e];
        }
      }
    }
    half8 A[3][2];
#pragma unroll
    for (int p = 0; p < 3; ++p)
#pragma unroll
      for (int tn = 0; tn < 2; ++tn)
        A[p][tn] = *(const half8*)(wb + p * 1024 + tn * 512);
#pragma unroll
    for (int ks = 0; ks < 16; ++ks) {
      const int cx = ((ks * 2 + hi) ^ sx) << 3;
      half8 b[4];
#pragma unroll
      for (int tp = 0; tp < 4; ++tp) b[tp] = *(const half8*)(rp + tp * 32 * AST + cx);
#pragma unroll
      for (int tn = 0; tn < 2; ++tn)
#pragma unroll
        for (int tp = 0; tp < 4; ++tp)
          acc[tn][tp] = __builtin_amdgcn_mfma_f32_32x32x16_f16(
              A[ks % 3][tn], b[tp], acc[tn][tp], 0, 0, 0);
      if (ks + 3 < 16) {
#pragma unroll
        for (int tn = 0; tn < 2; ++tn)
          A[ks % 3][tn] = *(const half8*)(wb + (ks + 3) * 1024 + tn * 512);
      }
    }
    float pocc[4] = {0.f, 0.f, 0.f, 0.f};
#pragma unroll
    for (int tn = 0; tn < 2; ++tn) {
      float4_t w0v = *(const float4_t*)(Wocc + 64 * w + 32 * tn + 4 * hi);
      float4_t w1v = *(const float4_t*)(Wocc + 64 * w + 32 * tn + 8 + 4 * hi);
      float4_t w2v = *(const float4_t*)(Wocc + 64 * w + 32 * tn + 16 + 4 * hi);
      float4_t w3v = *(const float4_t*)(Wocc + 64 * w + 32 * tn + 24 + 4 * hi);
#pragma unroll
      for (int tp = 0; tp < 4; ++tp) {
#pragma unroll
        for (int e = 0; e < 4; ++e) {
          pocc[tp] += fmaxf(acc[tn][tp][e], 0.f) * w0v[e];
          pocc[tp] += fmaxf(acc[tn][tp][4 + e], 0.f) * w1v[e];
          pocc[tp] += fmaxf(acc[tn][tp][8 + e], 0.f) * w2v[e];
          pocc[tp] += fmaxf(acc[tn][tp][12 + e], 0.f) * w3v[e];
        }
      }
    }
#pragma unroll
    for (int tp = 0; tp < 4; ++tp) {
      float s = pocc[tp];
      s += __shfl_xor(s, 32, 64);
      if (l < 32) occ_s[w][tp * 32 + p31] = s;
    }
  }
  __syncthreads();                                   // (6) occ partials ready
  if (t < M_PB) {
    out[m0 + t] = occ_s[0][t] + occ_s[1][t] + occ_s[2][t] + occ_s[3][t] + bocc[0];
  }
}

extern "C" void kernel_launch(void* const* d_in, const int* in_sizes, int n_in,
                              void* d_out, int out_size, void* d_ws, size_t ws_size,
                              hipStream_t stream) {
  const float* coords = (const float*)d_in[0];
  const float* W0   = (const float*)d_in[1];
  const float* b0   = (const float*)d_in[2];
  const float* W1   = (const float*)d_in[3];
  const float* b1   = (const float*)d_in[4];
  const float* W2   = (const float*)d_in[5];
  const float* b2   = (const float*)d_in[6];
  const float* Wocc = (const float*)d_in[7];
  const float* bocc = (const float*)d_in[8];
  const float* Wc   = (const float*)d_in[9];
  const float* bc   = (const float*)d_in[10];
  float* out = (float*)d_out;

  _Float16* ws = (_Float16*)d_ws;       // W0sw[16384] | W1sw[65536] | W2sw[65536]
  _Float16* W0sw = ws;
  _Float16* W1sw = ws + 16384;
  _Float16* W2sw = ws + 81920;

  prep<<<576, 256, 0, stream>>>(W0, W1, W2, ws);
  mlp_main<<<NPTS / M_PB, 256, 0, stream>>>(coords, W0sw, W1sw, W2sw,
                                            b0, b1, b2, Wocc, bocc, Wc, bc, out);
}